// Round 6
// baseline (330.909 us; speedup 1.0000x reference)
//
#include <hip/hip_runtime.h>

// LaplacianReg: B=32, V=65536, K=8, C=3, fp32 in/out.
// res[b,v,c] = ( d[b,v,c] + sum_k w[v,k]*d[b,idx[v,k],c] )^2,  d = out - tgt
//
// Round 6: L2-local gather, correctly this time.
//  - dt split into 4 batch-chunks of 8 batches: row = 8b*3c bf16 = 48 B;
//    chunk plane = 3.15 MB < 4 MiB per-XCD L2 (R4's 8-chunk/24B variant
//    octupled row-touches and ate the locality win).
//  - pass2 blocks read their REAL XCD via s_getreg(HW_REG_XCC_ID) and claim
//    v-tiles from their own chunk's atomic work queue (XCDs x and x+4 share
//    chunk x&3). Work-stealing across queues makes coverage exactly-once and
//    dispatch-independent (G16); wrong-XCD guesses only cost speed.
// Evidence: R5 full counters (Occ 95.6%, VALU 2.1%, HBM 4.2%, FETCH/WRITE
// compulsory) killed latency/MLP and request-count models; remaining model is
// IC random-line throughput -> make gathers XCD-L2-local.
#define BB 32
#define VV 65536
#define KK 8
#define CC 3

constexpr int NCHUNK = 4;             // batch chunks (2 XCDs per chunk)
constexpr int CB     = BB / NCHUNK;   // 8 batches per chunk
constexpr int CROW   = CB * CC;       // 24 elems per (chunk,v) row = 48 B
constexpr int CROWU  = CROW / 2;      // 12 uints per row

// ---- pass1 tile ----
constexpr int TV1   = 64;
constexpr int ROW   = BB * CC;        // 96
constexpr int PROW1 = ROW + 1;        // 97, LDS pad
constexpr int T1ELEMS = TV1 * ROW;    // 6144

// ---- pass2 tile ----
constexpr int TVG   = 64;             // v per claimed tile (4 lanes per v)
constexpr int PR2   = CROW + 1;       // 25
constexpr int NTILE = VV / TVG;       // 1024 tiles per chunk
constexpr int G2    = 4096;           // pass2 grid

__device__ __forceinline__ unsigned int f2bf(float f) {
  unsigned int u = __float_as_uint(f);
  u += 0x7FFFu + ((u >> 16) & 1u);    // round-to-nearest-even
  return u >> 16;
}
__device__ __forceinline__ float bflo(unsigned int u) { return __uint_as_float(u << 16); }
__device__ __forceinline__ float bfhi(unsigned int u) { return __uint_as_float(u & 0xFFFF0000u); }

struct U3 { unsigned int x, y, z; };  // 12B, 4B-aligned -> global_load_dwordx3

// ---------------------------------------------------------------------------
// Pass 1: dt[chunk][v][j] = bf16(out[b,v,c]-tgt[b,v,c]), chunk=b/8, j=(b%8)*3+c.
// Coalesced float4 reads, LDS transpose, coalesced uint4 writes per plane
// (TV1*48B = 3072B contiguous per plane per block). Also zeroes the 4 tile
// counters (kernel boundary publishes them to pass2).
// ---------------------------------------------------------------------------
__global__ __launch_bounds__(256) void lap_pass1_transpose_sub(
    const float* __restrict__ outp, const float* __restrict__ tgtp,
    unsigned int* __restrict__ dt, unsigned int* __restrict__ ctr) {
  __shared__ float tile[TV1 * PROW1];   // 24.8 KB
  const int t  = threadIdx.x;
  const int v0 = blockIdx.x * TV1;

  if (blockIdx.x == 0 && t < NCHUNK) atomicExch(&ctr[t], 0u);

  const float4* o4 = (const float4*)outp;
  const float4* t4 = (const float4*)tgtp;
  const int src_base4 = (v0 * CC) >> 2;           // exact: v0*CC % 4 == 0
  #pragma unroll
  for (int l4 = t; l4 < T1ELEMS / 4; l4 += 256) {
    int b  = l4 / (TV1 * CC / 4);                 // 48 float4 per b
    int j4 = l4 - b * (TV1 * CC / 4);
    int src = b * (VV * CC / 4) + src_base4 + j4;
    float4 a = o4[src];
    float4 g = t4[src];
    float dv[4] = {a.x - g.x, a.y - g.y, a.z - g.z, a.w - g.w};
    int j = 4 * j4;
    #pragma unroll
    for (int q = 0; q < 4; q++) {
      int jj = j + q;
      int vrel = jj / CC, c = jj - vrel * CC;
      tile[vrel * PROW1 + b * CC + c] = dv[q];
    }
  }
  __syncthreads();

  // 4 planes x 192 uint4 per block (region TV1*CROWU = 768 uints per plane).
  #pragma unroll
  for (int u = t; u < NCHUNK * (TV1 * CROWU / 4); u += 256) {
    int chunk = u / (TV1 * CROWU / 4);            // /192
    int i16   = u - chunk * (TV1 * CROWU / 4);
    int E = i16 * 8;                              // elem index in plane region
    unsigned int w[8];
    #pragma unroll
    for (int q = 0; q < 8; q++) {
      int ee = E + q;
      int vrel = ee / CROW, jj = ee - vrel * CROW;
      w[q] = f2bf(tile[vrel * PROW1 + chunk * CROW + jj]);
    }
    uint4 o;
    o.x = w[0] | (w[1] << 16);
    o.y = w[2] | (w[3] << 16);
    o.z = w[4] | (w[5] << 16);
    o.w = w[6] | (w[7] << 16);
    uint4* dst = (uint4*)(dt + (size_t)chunk * (VV * CROWU) + (size_t)v0 * CROWU);
    dst[i16] = o;
  }
}

// ---------------------------------------------------------------------------
// Pass 2: persistent-ish blocks. Block reads its XCD (HW_REG_XCC_ID, id=20,
// 4 bits) and claims tiles from chunk (xcd&3) first, stealing from other
// queues when empty. Per tile: 4 lanes per v (each lane = 2 batches x 3 c =
// one dwordx3 per gather row of 48 B), all gathers inside the 3.15 MB chunk
// plane -> resident in the local XCD L2. Coalesced float4 writeback.
// ---------------------------------------------------------------------------
__global__ __launch_bounds__(256) void lap_pass2_gather(
    const unsigned int* __restrict__ dt, const int* __restrict__ nidx,
    const float* __restrict__ nw, float* __restrict__ res,
    unsigned int* __restrict__ ctr) {
  __shared__ float rtile[TVG * PR2];   // 6.25 KB
  __shared__ int   idx_s[TVG * KK];    // 2 KB
  __shared__ float w_s[TVG * KK];      // 2 KB
  __shared__ int   s_claim[2];
  const int t = threadIdx.x;

  // getreg imm = ((size-1)<<11)|(offset<<6)|id ; XCC_ID: id=20, 4 bits.
  const int xcd = __builtin_amdgcn_s_getreg((3 << 11) | 20);
  const int myq = xcd & (NCHUNK - 1);

  for (;;) {
    if (t == 0) {
      int got = -1, gq = -1;
      #pragma unroll
      for (int a = 0; a < NCHUNK; a++) {
        int qq = (myq + a) & (NCHUNK - 1);
        unsigned int s = atomicAdd(&ctr[qq], 1u);
        if (s < (unsigned int)NTILE) { got = (int)s; gq = qq; break; }
      }
      s_claim[0] = got; s_claim[1] = gq;
    }
    __syncthreads();
    const int tilei = s_claim[0], q = s_claim[1];
    if (tilei < 0) break;
    const int v0 = tilei * TVG;

    // stage idx/w: 512 ints each, one int2/float2 per thread.
    ((int2*)idx_s)[t]  = ((const int2*)(nidx + (size_t)v0 * KK))[t];
    ((float2*)w_s)[t]  = ((const float2*)(nw + (size_t)v0 * KK))[t];
    __syncthreads();

    const unsigned int* dtc = dt + (size_t)q * (VV * CROWU);
    const int gr = t >> 2;              // v group: 64 per block
    const int la = t & 3;               // lane: batches q*8 + 2la, 2la+1
    const int v  = v0 + gr;

    const int4*   ip = (const int4*)&idx_s[gr * KK];
    const float4* wp = (const float4*)&w_s[gr * KK];
    int4   ia = ip[0], ib = ip[1];
    float4 wa = wp[0], wb = wp[1];
    int   nbk[KK] = {ia.x, ia.y, ia.z, ia.w, ib.x, ib.y, ib.z, ib.w};
    float wk[KK]  = {wa.x, wa.y, wa.z, wa.w, wb.x, wb.y, wb.z, wb.w};

    // self term (dwordx3 from own chunk row)
    U3 s = *(const U3*)(dtc + (size_t)v * CROWU + 3 * la);
    float x0 = bflo(s.x), y0 = bfhi(s.x), z0 = bflo(s.y);
    float x1 = bfhi(s.y), y1 = bflo(s.z), z1 = bfhi(s.z);

    #pragma unroll
    for (int k = 0; k < KK; k++) {
      U3 u = *(const U3*)(dtc + (size_t)nbk[k] * CROWU + 3 * la);
      const float wt = wk[k];
      x0 = fmaf(wt, bflo(u.x), x0);
      y0 = fmaf(wt, bfhi(u.x), y0);
      z0 = fmaf(wt, bflo(u.y), z0);
      x1 = fmaf(wt, bfhi(u.y), x1);
      y1 = fmaf(wt, bflo(u.z), y1);
      z1 = fmaf(wt, bfhi(u.z), z1);
    }
    float* rp = &rtile[gr * PR2 + 6 * la];
    rp[0] = x0 * x0; rp[1] = y0 * y0; rp[2] = z0 * z0;
    rp[3] = x1 * x1; rp[4] = y1 * y1; rp[5] = z1 * z1;
    __syncthreads();

    // writeback: 8 batches x 48 float4 (768 B contiguous per batch).
    float4* r4 = (float4*)res;
    const int dst_base4 = (v0 * CC) >> 2;         // tile*48, exact
    #pragma unroll
    for (int l4 = t; l4 < CB * (TVG * CC / 4); l4 += 256) {
      int bb = l4 / (TVG * CC / 4);               // /48
      int j4 = l4 - bb * (TVG * CC / 4);
      int b  = q * CB + bb;
      int j  = 4 * j4;
      float tmp[4];
      #pragma unroll
      for (int e = 0; e < 4; e++) {
        int jj = j + e;
        int vr = jj / CC, c = jj - vr * CC;
        tmp[e] = rtile[vr * PR2 + bb * CC + c];
      }
      r4[(size_t)b * (VV * CC / 4) + dst_base4 + j4] =
          make_float4(tmp[0], tmp[1], tmp[2], tmp[3]);
    }
    __syncthreads();   // rtile/idx_s reuse + s_claim rewrite safety
  }
}

// ---------------------------------------------------------------------------
// Fallback (ws too small): fused fp32 direct kernel, one thread per (b,v).
// ---------------------------------------------------------------------------
__global__ __launch_bounds__(256) void lap_fused_fallback(
    const float* __restrict__ outp, const float* __restrict__ tgtp,
    const int* __restrict__ nidx, const float* __restrict__ nw,
    float* __restrict__ res) {
  int tid = blockIdx.x * 256 + threadIdx.x;
  if (tid >= BB * VV) return;
  int v = tid & (VV - 1);
  int b = tid >> 16;
  float ax = 0.f, ay = 0.f, az = 0.f;
  #pragma unroll
  for (int k = 0; k < KK; k++) {
    int   nb = nidx[v * KK + k];
    float wt = nw[v * KK + k];
    const float* po = outp + ((size_t)b * VV + nb) * CC;
    const float* pt = tgtp + ((size_t)b * VV + nb) * CC;
    ax = fmaf(wt, po[0] - pt[0], ax);
    ay = fmaf(wt, po[1] - pt[1], ay);
    az = fmaf(wt, po[2] - pt[2], az);
  }
  const float* so = outp + (size_t)tid * CC;
  const float* st = tgtp + (size_t)tid * CC;
  float dx = so[0] - st[0] + ax;
  float dy = so[1] - st[1] + ay;
  float dz = so[2] - st[2] + az;
  float* rp = res + (size_t)tid * CC;
  rp[0] = dx * dx; rp[1] = dy * dy; rp[2] = dz * dz;
}

extern "C" void kernel_launch(void* const* d_in, const int* in_sizes, int n_in,
                              void* d_out, int out_size, void* d_ws, size_t ws_size,
                              hipStream_t stream) {
  const float* outp = (const float*)d_in[0];
  const float* tgtp = (const float*)d_in[1];
  const int*   nidx = (const int*)d_in[2];
  const float* nw   = (const float*)d_in[3];
  float* res = (float*)d_out;

  const size_t dt_bytes = (size_t)VV * ROW * 2;   // 12.6 MB bf16
  if (ws_size >= dt_bytes + 4 * sizeof(unsigned int)) {
    unsigned int* dt  = (unsigned int*)d_ws;
    unsigned int* ctr = dt + (size_t)VV * CROWU * NCHUNK;  // right after dt
    lap_pass1_transpose_sub<<<VV / TV1, 256, 0, stream>>>(outp, tgtp, dt, ctr);
    lap_pass2_gather<<<G2, 256, 0, stream>>>(dt, nidx, nw, res, ctr);
  } else {
    lap_fused_fallback<<<(BB * VV) / 256, 256, 0, stream>>>(outp, tgtp, nidx, nw, res);
  }
}

// Round 7
// 111.905 us; speedup vs baseline: 2.9571x; 2.9571x over previous
//
#include <hip/hip_runtime.h>

// LaplacianReg: B=32, V=65536, K=8, C=3, fp32 in/out.
// res[b,v,c] = ( d[b,v,c] + sum_k w[v,k]*d[b,idx[v,k],c] )^2,  d = out - tgt
//
// Round 7: halve the gather's Infinity-Cache line-touches. Evidence (R0-R6):
// every gather organization converges to the same ~55us phase2 -- random IC
// line-touch throughput (~2.5 TB/s) is the wall; occupancy/fusion/chunking all
// null or negative. The only remaining lever is touches-per-(v,k): a 192B bf16
// row spans 2 lines; a BLOCK-FLOAT row (one dword per batch: shared 5-bit exp
// + 3x(sign+8mant) for the 3 channels) is exactly 128B = ONE line.
//   touches: V*K*2 = 1.05M -> V*K = 524K (-50%).
// Accuracy: abs err per value <= triplet_max * 2^-9 -- same absolute bound as
// bf16 at the triplet max (bf16 measured absmax 0.25), unlike fp8 (16x worse).
// Structure is otherwise EXACTLY R0's two-pass (best measured non-coop).
#define BB 32
#define VV 65536
#define KK 8
#define CC 3

constexpr int TV   = 64;              // v-tile per block (grid 1024)
constexpr int ROW  = BB * CC;         // 96 elems per transposed v-row
constexpr int PROW = ROW + 1;         // LDS pad
constexpr int TILE_ELEMS = TV * ROW;  // 6144
constexpr int RDW  = BB;              // 32 dwords per encoded row = 128B

// ---- block-float triplet codec: u = [e5|s2 m2|s1 m1|s0 m0] -----------------
// value i magnitude = m_i * 2^(e5-15-8); exact for the triplet max's leading
// 8 mantissa bits (same absolute quantum as bf16 at the max).
__device__ __forceinline__ unsigned int enc3(float x0, float x1, float x2) {
  float a0 = fabsf(x0), a1 = fabsf(x1), a2 = fabsf(x2);
  float A  = fmaxf(a0, fmaxf(a1, a2));
  if (A == 0.f) return 0u;
  int ex;
  (void)frexpf(A, &ex);               // A = f*2^ex, f in [0.5,1)
  int e5 = ex + 15;
  e5 = e5 < 0 ? 0 : (e5 > 31 ? 31 : e5);
  float s = ldexpf(1.f, 23 - e5);     // 2^(8-ex) after bias
  unsigned m0 = (unsigned)fminf(fmaf(a0, s, 0.5f), 255.f);
  unsigned m1 = (unsigned)fminf(fmaf(a1, s, 0.5f), 255.f);
  unsigned m2 = (unsigned)fminf(fmaf(a2, s, 0.5f), 255.f);
  unsigned s0 = __float_as_uint(x0) >> 31;
  unsigned s1 = __float_as_uint(x1) >> 31;
  unsigned s2 = __float_as_uint(x2) >> 31;
  return ((unsigned)e5 << 27) | (s2 << 26) | (m2 << 18)
       | (s1 << 17) | (m1 << 9) | (s0 << 8) | m0;
}
__device__ __forceinline__ void dec3(unsigned int u,
                                     float& v0, float& v1, float& v2) {
  float sc  = ldexpf(1.f, (int)(u >> 27) - 23);   // 2^(ex-8)
  float nsc = -sc;
  v0 = (float)(u & 255u)         * (((u >> 8)  & 1u) ? nsc : sc);
  v1 = (float)((u >> 9) & 255u)  * (((u >> 17) & 1u) ? nsc : sc);
  v2 = (float)((u >> 18) & 255u) * (((u >> 26) & 1u) ? nsc : sc);
}

// ---------------------------------------------------------------------------
// Pass 1: dt[v][b] = enc3(d[b,v,0..2]) via LDS tile transpose.
// Coalesced float4 reads; coalesced uint4 (4 batches) writes. 128B rows.
// ---------------------------------------------------------------------------
__global__ __launch_bounds__(256) void lap_pass1_encode(
    const float* __restrict__ outp, const float* __restrict__ tgtp,
    unsigned int* __restrict__ dt) {
  __shared__ float tile[TV * PROW];   // 24.8 KB
  const int t  = threadIdx.x;
  const int v0 = blockIdx.x * TV;

  const float4* o4 = (const float4*)outp;
  const float4* t4 = (const float4*)tgtp;
  const int src_base4 = (v0 * CC) >> 2;           // exact: v0 multiple of 64
  #pragma unroll
  for (int l4 = t; l4 < TILE_ELEMS / 4; l4 += 256) {
    int b  = l4 / (TV * CC / 4);                  // 48 float4 per b
    int j4 = l4 - b * (TV * CC / 4);
    int src = b * (VV * CC / 4) + src_base4 + j4;
    float4 a = o4[src];
    float4 g = t4[src];
    float dv[4] = {a.x - g.x, a.y - g.y, a.z - g.z, a.w - g.w};
    int j = 4 * j4;
    #pragma unroll
    for (int q = 0; q < 4; q++) {
      int jj = j + q;
      int vrel = jj / CC, c = jj - vrel * CC;
      tile[vrel * PROW + b * CC + c] = dv[q];
    }
  }
  __syncthreads();

  // Encode 64 v x 32 b = 2048 dwords = 512 uint4 (4 batches per uint4).
  uint4* dst = (uint4*)(dt + (size_t)v0 * RDW);
  #pragma unroll
  for (int u = t; u < TV * BB / 4; u += 256) {
    int vrel = u >> 3;                // 8 uint4 per v
    int b0   = (u & 7) * 4;
    unsigned int w[4];
    #pragma unroll
    for (int q = 0; q < 4; q++) {
      const float* p = &tile[vrel * PROW + (b0 + q) * CC];
      w[q] = enc3(p[0], p[1], p[2]);
    }
    uint4 o; o.x = w[0]; o.y = w[1]; o.z = w[2]; o.w = w[3];
    dst[u] = o;
  }
}

// ---------------------------------------------------------------------------
// Pass 2: 16-lane group per v, lane l covers batches 2l,2l+1 -> dwords
// 2l,2l+1 of the 128B row = one dwordx2 per gather row, 16 lanes cover the
// row exactly (one cache line per (v,k)). idx/w staged in LDS. Output
// restaged via LDS for coalesced fp32 float4 writes in (B,V,C).
// ---------------------------------------------------------------------------
__global__ __launch_bounds__(256) void lap_pass2_gather(
    const unsigned int* __restrict__ dt, const int* __restrict__ nidx,
    const float* __restrict__ nw, float* __restrict__ res) {
  __shared__ float rtile[TV * PROW];  // 24.8 KB
  __shared__ int   idx_s[TV * KK];    // 2 KB
  __shared__ float w_s[TV * KK];      // 2 KB
  const int t  = threadIdx.x;
  const int v0 = blockIdx.x * TV;

  // stage idx/w: 512 ints each; one int2/float2 per thread.
  ((int2*)idx_s)[t]  = ((const int2*)(nidx + (size_t)v0 * KK))[t];
  ((float2*)w_s)[t]  = ((const float2*)(nw + (size_t)v0 * KK))[t];
  __syncthreads();

  const int g = t >> 4;   // 16 groups per block
  const int l = t & 15;   // lane within group; covers b = 2l, 2l+1
  #pragma unroll 2
  for (int i = 0; i < TV / 16; i++) {
    const int vrel = i * 16 + g;
    const int v    = v0 + vrel;

    const int4*   ip = (const int4*)&idx_s[vrel * KK];
    const float4* wp = (const float4*)&w_s[vrel * KK];
    int4   ia = ip[0], ib = ip[1];
    float4 wa = wp[0], wb = wp[1];
    int   nbk[KK] = {ia.x, ia.y, ia.z, ia.w, ib.x, ib.y, ib.z, ib.w};
    float wk[KK]  = {wa.x, wa.y, wa.z, wa.w, wb.x, wb.y, wb.z, wb.w};

    // self term (one dwordx2, decode)
    uint2 su = *(const uint2*)(dt + (size_t)v * RDW + 2 * l);
    float x0, y0, z0, x1, y1, z1;
    dec3(su.x, x0, y0, z0);
    dec3(su.y, x1, y1, z1);

    #pragma unroll
    for (int k = 0; k < KK; k++) {
      uint2 u2 = *(const uint2*)(dt + (size_t)nbk[k] * RDW + 2 * l);
      const float wt = wk[k];
      float p0, p1, p2, p3, p4, p5;
      dec3(u2.x, p0, p1, p2);
      dec3(u2.y, p3, p4, p5);
      x0 = fmaf(wt, p0, x0);
      y0 = fmaf(wt, p1, y0);
      z0 = fmaf(wt, p2, z0);
      x1 = fmaf(wt, p3, x1);
      y1 = fmaf(wt, p4, y1);
      z1 = fmaf(wt, p5, z1);
    }
    float* rp = &rtile[vrel * PROW + 6 * l];  // (b=2l,c0..2),(b=2l+1,c0..2)
    rp[0] = x0 * x0; rp[1] = y0 * y0; rp[2] = z0 * z0;
    rp[3] = x1 * x1; rp[4] = y1 * y1; rp[5] = z1 * z1;
  }
  __syncthreads();

  // Coalesced writeback to (B,V,C).
  float4* r4 = (float4*)res;
  const int dst_base4 = (v0 * CC) >> 2;
  #pragma unroll
  for (int l4 = t; l4 < TILE_ELEMS / 4; l4 += 256) {
    int b  = l4 / (TV * CC / 4);
    int j4 = l4 - b * (TV * CC / 4);
    int j  = 4 * j4;
    float tmp[4];
    #pragma unroll
    for (int q = 0; q < 4; q++) {
      int jj = j + q;
      int vrel = jj / CC, c = jj - vrel * CC;
      tmp[q] = rtile[vrel * PROW + b * CC + c];
    }
    r4[b * (VV * CC / 4) + dst_base4 + j4] = make_float4(tmp[0], tmp[1], tmp[2], tmp[3]);
  }
}

// ---------------------------------------------------------------------------
// Fallback (ws too small): fused fp32 direct kernel, one thread per (b,v).
// ---------------------------------------------------------------------------
__global__ __launch_bounds__(256) void lap_fused_fallback(
    const float* __restrict__ outp, const float* __restrict__ tgtp,
    const int* __restrict__ nidx, const float* __restrict__ nw,
    float* __restrict__ res) {
  int tid = blockIdx.x * 256 + threadIdx.x;
  if (tid >= BB * VV) return;
  int v = tid & (VV - 1);
  int b = tid >> 16;
  float ax = 0.f, ay = 0.f, az = 0.f;
  #pragma unroll
  for (int k = 0; k < KK; k++) {
    int   nb = nidx[v * KK + k];
    float wt = nw[v * KK + k];
    const float* po = outp + ((size_t)b * VV + nb) * CC;
    const float* pt = tgtp + ((size_t)b * VV + nb) * CC;
    ax = fmaf(wt, po[0] - pt[0], ax);
    ay = fmaf(wt, po[1] - pt[1], ay);
    az = fmaf(wt, po[2] - pt[2], az);
  }
  const float* so = outp + (size_t)tid * CC;
  const float* st = tgtp + (size_t)tid * CC;
  float dx = so[0] - st[0] + ax;
  float dy = so[1] - st[1] + ay;
  float dz = so[2] - st[2] + az;
  float* rp = res + (size_t)tid * CC;
  rp[0] = dx * dx; rp[1] = dy * dy; rp[2] = dz * dz;
}

extern "C" void kernel_launch(void* const* d_in, const int* in_sizes, int n_in,
                              void* d_out, int out_size, void* d_ws, size_t ws_size,
                              hipStream_t stream) {
  const float* outp = (const float*)d_in[0];
  const float* tgtp = (const float*)d_in[1];
  const int*   nidx = (const int*)d_in[2];
  const float* nw   = (const float*)d_in[3];
  float* res = (float*)d_out;

  const size_t dt_bytes = (size_t)VV * RDW * 4;   // 8.4 MB encoded
  if (ws_size >= dt_bytes) {
    unsigned int* dt = (unsigned int*)d_ws;
    lap_pass1_encode<<<VV / TV, 256, 0, stream>>>(outp, tgtp, dt);
    lap_pass2_gather<<<VV / TV, 256, 0, stream>>>(dt, nidx, nw, res);
  } else {
    lap_fused_fallback<<<(BB * VV) / 256, 256, 0, stream>>>(outp, tgtp, nidx, nw, res);
  }
}